// Round 3
// 486.351 us; speedup vs baseline: 1.0353x; 1.0353x over previous
//
#include <hip/hip_runtime.h>
#include <hip/hip_bf16.h>

// EMA scan: a_t = w*x_t + (1-w)*a_{t-1}, y_t = a_t
// x: [B,T,F] fp32, initial_state: [B,F] fp32, smooth: [1] fp32 (clipped to [0,1])
// Exact chunked-scan decomposition (linear recurrence, constant coefficient):
//   phase 1: per-chunk local scan from zero  -> chunk-final P_c  (reads x once,
//            normal caching loads: this pass warms L3 with x for phase 3)
//   phase 2: weighted Kogge-Stone scan over chunks in LDS -> exact carry-in A_c
//            A_c = dL^c * A0 + sum_{j<c} dL^{c-1-j} P_j
//   phase 3: re-scan chunk seeded with A_c, write y. Chunk traversal REVERSED
//            so first-scheduled blocks consume the most-recently-cached tail of
//            x; x loads and y stores are NON-TEMPORAL so phase 3 does not evict
//            the still-resident portion of x from the 256 MiB L3.
// NOTE: __builtin_nontemporal_* requires clang native vectors (ext_vector_type);
// HIP_vector_type float4 is rejected. f4v is the ext-vector alias used there.
#define B_   16
#define T_   8192
#define F_   512
#define F4_  (F_ / 4)       // 128 float4 per (b,t) row
#define BF4_ (B_ * F4_)     // 2048 columns (b,f4)

typedef float f4v __attribute__((ext_vector_type(4)));

__device__ __forceinline__ float read_w(const float* smooth) {
    float w = smooth[0];
    return fminf(fmaxf(w, 0.0f), 1.0f);
}

// Phase 1: per-chunk local scan from zero state; store chunk-final accumulator.
__global__ __launch_bounds__(256, 4) void ema_phase1(const float* __restrict__ x,
                                                     const float* __restrict__ smooth,
                                                     float4* __restrict__ carry,
                                                     int C, int L) {
    const int tid = blockIdx.x * blockDim.x + threadIdx.x;   // 0 .. B_*C*F4_-1
    const int lc  = 31 - __clz(C);                           // C is pow2
    const int f4  = tid & (F4_ - 1);
    const int c   = (tid >> 7) & (C - 1);                    // F4_ == 1<<7
    const int b   = tid >> (7 + lc);
    const float w = read_w(smooth);
    const float d = 1.0f - w;

    const float4* xp = reinterpret_cast<const float4*>(x)
                     + (size_t)(b * T_ + c * L) * F4_ + f4;
    float4 a = make_float4(0.f, 0.f, 0.f, 0.f);
#pragma unroll 8
    for (int s = 0; s < L; ++s) {
        float4 xv = xp[(size_t)s * F4_];
        a.x = fmaf(d, a.x, w * xv.x);
        a.y = fmaf(d, a.y, w * xv.y);
        a.z = fmaf(d, a.z, w * xv.z);
        a.w = fmaf(d, a.w, w * xv.w);
    }
    carry[(size_t)c * BF4_ + b * F4_ + f4] = a;
}

// Phase 2: weighted inclusive Kogge-Stone scan along the chunk axis in LDS.
// In-place: carry[c] (chunk-final from zero) becomes exact carry-IN for chunk c.
// Block = 256 threads = (256/C) columns x C chunk positions. Requires C <= 256.
__global__ __launch_bounds__(256) void ema_phase2(const float* __restrict__ init,
                                                  const float* __restrict__ smooth,
                                                  float4* __restrict__ carry,
                                                  int C, int L) {
    __shared__ float4 S[256];
    const float w  = read_w(smooth);
    const float d  = 1.0f - w;
    const float dL = powf(d, (float)L);

    const int lc       = 31 - __clz(C);
    const int c        = threadIdx.x & (C - 1);
    const int colLocal = threadIdx.x >> lc;
    const int col      = blockIdx.x * (256 >> lc) + colLocal;   // b*F4_ + f4

    float4 t = carry[(size_t)c * BF4_ + col];   // P_c
    S[threadIdx.x] = t;

    float mk = dL;
    for (int step = 1; step < C; step <<= 1) {
        __syncthreads();
        float4 add = make_float4(0.f, 0.f, 0.f, 0.f);
        if (c >= step) add = S[threadIdx.x - step];
        __syncthreads();
        t.x = fmaf(mk, add.x, t.x);
        t.y = fmaf(mk, add.y, t.y);
        t.z = fmaf(mk, add.z, t.z);
        t.w = fmaf(mk, add.w, t.w);
        S[threadIdx.x] = t;
        mk *= mk;
    }
    __syncthreads();
    // t (=S[c]) is inclusive prefix; carry-in A_c = dL^c * A0 + S_{c-1}
    float4 A = make_float4(0.f, 0.f, 0.f, 0.f);
    if (c > 0) A = S[threadIdx.x - 1];
    const float4 A0 = reinterpret_cast<const float4*>(init)[col];
    const float dc = powf(dL, (float)c);
    A.x = fmaf(dc, A0.x, A.x);
    A.y = fmaf(dc, A0.y, A.y);
    A.z = fmaf(dc, A0.z, A.z);
    A.w = fmaf(dc, A0.w, A.w);
    carry[(size_t)c * BF4_ + col] = A;
}

// Phase 3: re-scan each chunk seeded with its exact carry-in, write y.
// Reversed traversal + non-temporal accesses for L3 reuse of x from phase 1.
__global__ __launch_bounds__(256, 4) void ema_phase3(const float* __restrict__ x,
                                                     const float* __restrict__ smooth,
                                                     const float4* __restrict__ carry,
                                                     float* __restrict__ y,
                                                     int C, int L) {
    const int tid = blockIdx.x * blockDim.x + threadIdx.x;
    const int lc  = 31 - __clz(C);
    const int f4  = tid & (F4_ - 1);
    const int m   = (B_ * C - 1) - (tid >> 7);    // reversed row-chunk index
    const int c   = m & (C - 1);
    const int b   = m >> lc;
    const float w = read_w(smooth);
    const float d = 1.0f - w;

    const size_t base = (size_t)(b * T_ + c * L) * F4_ + f4;
    const f4v* xp = reinterpret_cast<const f4v*>(x) + base;
    f4v*       yp = reinterpret_cast<f4v*>(y) + base;

    float4 a = carry[(size_t)c * BF4_ + b * F4_ + f4];
#pragma unroll 8
    for (int s = 0; s < L; ++s) {
        f4v xv = __builtin_nontemporal_load(&xp[(size_t)s * F4_]);
        a.x = fmaf(d, a.x, w * xv.x);
        a.y = fmaf(d, a.y, w * xv.y);
        a.z = fmaf(d, a.z, w * xv.z);
        a.w = fmaf(d, a.w, w * xv.w);
        f4v out;
        out.x = a.x; out.y = a.y; out.z = a.z; out.w = a.w;
        __builtin_nontemporal_store(out, &yp[(size_t)s * F4_]);
    }
}

extern "C" void kernel_launch(void* const* d_in, const int* in_sizes, int n_in,
                              void* d_out, int out_size, void* d_ws, size_t ws_size,
                              hipStream_t stream) {
    const float* x      = (const float*)d_in[0];
    const float* init   = (const float*)d_in[1];
    const float* smooth = (const float*)d_in[2];
    float*       y      = (float*)d_out;
    float4*      carry  = (float4*)d_ws;

    // C chunks along T; workspace needs C * B * F floats (4 MiB at C=128).
    int C = 128;
    while (C > 1 && (size_t)C * BF4_ * sizeof(float4) > ws_size) C >>= 1;
    const int L = T_ / C;

    const int threads13 = B_ * C * F4_;            // phase 1/3 thread count
    const int cpb       = 256 / C;                 // phase 2 columns per block
    ema_phase1<<<threads13 / 256, 256, 0, stream>>>(x, smooth, carry, C, L);
    ema_phase2<<<BF4_ / cpb,      256, 0, stream>>>(init, smooth, carry, C, L);
    ema_phase3<<<threads13 / 256, 256, 0, stream>>>(x, smooth, carry, y, C, L);
}